// Round 10
// baseline (326.488 us; speedup 1.0000x reference)
//
#include <hip/hip_runtime.h>
#include <hip/hip_fp16.h>

typedef _Float16 f16x8 __attribute__((ext_vector_type(8)));
typedef _Float16 f16x4 __attribute__((ext_vector_type(4)));
typedef _Float16 f16x2 __attribute__((ext_vector_type(2)));
typedef float    f32x16 __attribute__((ext_vector_type(16)));
typedef float    f32x4 __attribute__((ext_vector_type(4)));

#define SH 264   // H row stride (fp16): 256+8 (measured best vs chunk-major)
#define SE 56    // E row stride (fp16)
#define PTS 128  // points per block

struct LayerPtrs {
  const float* w[8];
  const float* b[8];
};

// Weight fragments in d_ws, A-operand layout for mfma_f32_32x32x16_f16:
//   m = mtile*32 + (lane&31), k = kc*16 + (lane>>5)*8 + j ; value = W[k][m]
// index = WOFF[l] + (kc*8 + mtile)*64 + lane, element j.
__global__ void prep_weights(LayerPtrs P, f16x8* __restrict__ wf) {
  int gid = blockIdx.x * 256 + threadIdx.x;
  if (gid >= 60416) return;
  const int OFF[9] = {0,1536,9728,17920,26112,35840,44032,52224,60416};
  int l = 0;
  while (gid >= OFF[l+1]) ++l;
  int f = gid - OFF[l];
  int lane = f & 63;
  int t = f >> 6;
  int mtile = t & 7;
  int kc = t >> 3;
  int col = mtile * 32 + (lane & 31);
  int kb  = (lane >> 5) * 8;
  const float* w = P.w[l];
  f16x8 v;
#pragma unroll
  for (int j = 0; j < 8; ++j) {
    float x = 0.f;
    if (l == 4) {
      if (kc < 3) {
        int k = kc * 16 + kb + j;
        if (k < 39) x = w[k * 256 + col];
      } else {
        int k = (kc - 3) * 16 + kb + j;
        x = w[(39 + k) * 256 + col];
      }
    } else if (l == 0) {
      int k = kc * 16 + kb + j;
      if (k < 39) x = w[k * 256 + col];
    } else {
      int k = kc * 16 + kb + j;
      x = w[k * 256 + col];
    }
    v[j] = (_Float16)x;
  }
  wf[gid] = v;
}

struct WPre { f16x8 a0, a1; };          // kc0 weight frags (2 m-tiles)
struct BPre { f32x4 v[8]; };            // bias quads: [mt*4+g]

__device__ __forceinline__ WPre wpre(const f16x8* __restrict__ wb) {
  WPre p; p.a0 = wb[0]; p.a1 = wb[64]; return p;
}

__device__ __forceinline__ BPre bias_pre(const float* __restrict__ bp, int h) {
  BPre r;
#pragma unroll
  for (int mt = 0; mt < 2; ++mt)
#pragma unroll
    for (int g = 0; g < 4; ++g)
      r.v[mt * 4 + g] = *(const f32x4*)&bp[mt * 32 + 8 * g + 4 * h];
  return r;
}

__device__ __forceinline__ void zero_acc(f32x16 acc[2][4]) {
#pragma unroll
  for (int mt = 0; mt < 2; ++mt)
#pragma unroll
    for (int nt = 0; nt < 4; ++nt)
#pragma unroll
      for (int r = 0; r < 16; ++r) acc[mt][nt][r] = 0.f;
}

// Wave = 64 hidden (2 m-tiles) x 128 points (4 n-tiles): 8 MFMA per kc.
// PRE: kc0's weight frags come pre-loaded (fetched before the last barrier).
template<int NKC, bool PRE>
__device__ __forceinline__ void mm(const f16x8* __restrict__ wb,
                                   const _Float16* __restrict__ b0,
                                   const _Float16* __restrict__ b1,
                                   const _Float16* __restrict__ b2,
                                   const _Float16* __restrict__ b3,
                                   f32x16 acc[2][4], WPre p) {
#pragma unroll
  for (int kc = 0; kc < NKC; ++kc) {
    f16x8 a0 = (PRE && kc == 0) ? p.a0 : wb[(kc * 8 + 0) * 64];
    f16x8 a1 = (PRE && kc == 0) ? p.a1 : wb[(kc * 8 + 1) * 64];
    f16x8 v0 = *(const f16x8*)(b0 + kc * 16);
    f16x8 v1 = *(const f16x8*)(b1 + kc * 16);
    f16x8 v2 = *(const f16x8*)(b2 + kc * 16);
    f16x8 v3 = *(const f16x8*)(b3 + kc * 16);
    acc[0][0] = __builtin_amdgcn_mfma_f32_32x32x16_f16(a0, v0, acc[0][0], 0, 0, 0);
    acc[0][1] = __builtin_amdgcn_mfma_f32_32x32x16_f16(a0, v1, acc[0][1], 0, 0, 0);
    acc[0][2] = __builtin_amdgcn_mfma_f32_32x32x16_f16(a0, v2, acc[0][2], 0, 0, 0);
    acc[0][3] = __builtin_amdgcn_mfma_f32_32x32x16_f16(a0, v3, acc[0][3], 0, 0, 0);
    acc[1][0] = __builtin_amdgcn_mfma_f32_32x32x16_f16(a1, v0, acc[1][0], 0, 0, 0);
    acc[1][1] = __builtin_amdgcn_mfma_f32_32x32x16_f16(a1, v1, acc[1][1], 0, 0, 0);
    acc[1][2] = __builtin_amdgcn_mfma_f32_32x32x16_f16(a1, v2, acc[1][2], 0, 0, 0);
    acc[1][3] = __builtin_amdgcn_mfma_f32_32x32x16_f16(a1, v3, acc[1][3], 0, 0, 0);
  }
}

// bias + relu + packed cvt: 4 add, 4 max, 2 cvt_pkrtz per quad
__device__ __forceinline__ f16x4 relu4(float a0, float a1, float a2, float a3,
                                       f32x4 b) {
  f16x2 lo = __builtin_bit_cast(f16x2,
      __builtin_amdgcn_cvt_pkrtz(fmaxf(a0 + b[0], 0.f), fmaxf(a1 + b[1], 0.f)));
  f16x2 hi = __builtin_bit_cast(f16x2,
      __builtin_amdgcn_cvt_pkrtz(fmaxf(a2 + b[2], 0.f), fmaxf(a3 + b[3], 0.f)));
  union { f16x4 v; f16x2 h[2]; } u;
  u.h[0] = lo; u.h[1] = hi;
  return u.v;
}

// C/D 32x32: col(point) = lane&31, row(hidden) = (reg&3) + 8*(reg>>2) + 4*(lane>>5)
__device__ __forceinline__ void store_act(f32x16 acc[2][4], const BPre& bp, int wg,
                                          int lane, _Float16* __restrict__ H) {
  int p0 = lane & 31, h = lane >> 5;
#pragma unroll
  for (int mt = 0; mt < 2; ++mt) {
    int hb = wg * 64 + mt * 32 + 4 * h;
#pragma unroll
    for (int g = 0; g < 4; ++g) {
      f32x4 bv = bp.v[mt * 4 + g];
#pragma unroll
      for (int nt = 0; nt < 4; ++nt) {
        f16x4 o = relu4(acc[mt][nt][4 * g + 0], acc[mt][nt][4 * g + 1],
                        acc[mt][nt][4 * g + 2], acc[mt][nt][4 * g + 3], bv);
        *(f16x4*)&H[(nt * 32 + p0) * SH + hb + 8 * g] = o;
      }
    }
  }
}

__global__ __launch_bounds__(256, 2)
void mlp_fused(const float* __restrict__ points,
               LayerPtrs P,
               const f16x8* __restrict__ wf,
               const float* __restrict__ wsdf,
               const float* __restrict__ bsdf,
               float* __restrict__ out) {
  __shared__ __align__(16) _Float16 H[PTS * SH];   // 67584 B
  __shared__ __align__(16) _Float16 E[PTS * SE];   // 14336 B -> 81920 total, 2 blocks/CU
  const int tid = threadIdx.x;
  const int blk = blockIdx.x;

  const int lane = tid & 63;
  const int wg   = tid >> 6;          // wave -> hidden slice [64*wg, 64*wg+64)
  const int p0   = lane & 31;
  const int h    = lane >> 5;

  const f16x8* wb = wf + (wg * 2) * 64 + lane;   // + WOFF[l] + (kc*8+mt)*64
  const int WOFF[8] = {0,1536,9728,17920,26112,35840,44032,52224};

  // Prefetch L0 weights before the (long) embedding VALU phase.
  WPre wp = wpre(wb + WOFF[0]);

  // ---- embedding into E: cols 0..38 = [sin(18)|cos(18)|xyz], 39..55 zero ----
  if (tid < PTS) {
    int p = blk * PTS + tid;
    float xyz[3] = {points[p * 3 + 0], points[p * 3 + 1], points[p * 3 + 2]};
    _Float16* row = &E[tid * SE];
#pragma unroll
    for (int c = 0; c < 3; ++c) {
      float fr = 1.f;
#pragma unroll
      for (int k = 0; k < 6; ++k) {
        float e = xyz[c] * fr;
        row[c * 6 + k]      = (_Float16)sinf(e);
        row[18 + c * 6 + k] = (_Float16)cosf(e);
        fr *= 2.f;
      }
      row[36 + c] = (_Float16)xyz[c];
    }
#pragma unroll
    for (int c = 39; c < SE; ++c) row[c] = (_Float16)0.f;
  }
  __syncthreads();

  const _Float16* e0 = &E[p0 * SE + h * 8];
  const _Float16* e1 = &E[(32 + p0) * SE + h * 8];
  const _Float16* e2 = &E[(64 + p0) * SE + h * 8];
  const _Float16* e3 = &E[(96 + p0) * SE + h * 8];
  const _Float16* h0 = &H[p0 * SH + h * 8];
  const _Float16* h1 = &H[(32 + p0) * SH + h * 8];
  const _Float16* h2 = &H[(64 + p0) * SH + h * 8];
  const _Float16* h3 = &H[(96 + p0) * SH + h * 8];

  f32x16 acc[2][4];
  BPre bp;

  // L0: read E, write H (disjoint -> no barrier between mm and store)
  zero_acc(acc);
  mm<3, true>(wb + WOFF[0], e0, e1, e2, e3, acc, wp);
  bp = bias_pre(P.b[0] + wg * 64, h);     // current-layer bias, pre-barrier
  wp = wpre(wb + WOFF[1]);                // next-layer kc0 weights
  store_act(acc, bp, wg, lane, H);
  __syncthreads();

  // L1..L3: in-place H
#pragma unroll
  for (int l = 1; l < 4; ++l) {
    zero_acc(acc);
    mm<16, true>(wb + WOFF[l], h0, h1, h2, h3, acc, wp);
    bp = bias_pre(P.b[l] + wg * 64, h);
    wp = wpre(wb + WOFF[l + 1]);
    __syncthreads();
    store_act(acc, bp, wg, lane, H);
    __syncthreads();
  }

  // L4: concat input = E (3 kc, prefetched) + H (16 kc)
  zero_acc(acc);
  mm<3, true>(wb + WOFF[4], e0, e1, e2, e3, acc, wp);
  mm<16, false>(wb + WOFF[4] + 3 * 512, h0, h1, h2, h3, acc, wp);
  bp = bias_pre(P.b[4] + wg * 64, h);
  wp = wpre(wb + WOFF[5]);
  __syncthreads();
  store_act(acc, bp, wg, lane, H);
  __syncthreads();

  // L5..L7
#pragma unroll
  for (int l = 5; l < 8; ++l) {
    zero_acc(acc);
    mm<16, true>(wb + WOFF[l], h0, h1, h2, h3, acc, wp);
    bp = bias_pre(P.b[l] + wg * 64, h);
    wp = wpre(wb + WOFF[l < 7 ? l + 1 : 7]);   // l=7: harmless dummy
    __syncthreads();
    store_act(acc, bp, wg, lane, H);
    __syncthreads();
  }

  // ---- SDF head: 2 threads per point (PTS=128, 256 threads) ----
  {
    const int p = tid >> 1, part = tid & 1;
    float a = 0.f;
    const _Float16* xr = &H[p * SH + part * 128];
#pragma unroll
    for (int j = 0; j < 16; ++j) {
      f16x8 hh = *(const f16x8*)&xr[j * 8];
      f32x4 wa = *(const f32x4*)&wsdf[part * 128 + j * 8];
      f32x4 wc = *(const f32x4*)&wsdf[part * 128 + j * 8 + 4];
      a += (float)hh[0] * wa[0] + (float)hh[1] * wa[1]
         + (float)hh[2] * wa[2] + (float)hh[3] * wa[3]
         + (float)hh[4] * wc[0] + (float)hh[5] * wc[1]
         + (float)hh[6] * wc[2] + (float)hh[7] * wc[3];
    }
    a += __shfl_down(a, 1);
    if (part == 0) out[blk * PTS + p] = a + bsdf[0];
  }
}

extern "C" void kernel_launch(void* const* d_in, const int* in_sizes, int n_in,
                              void* d_out, int out_size, void* d_ws, size_t ws_size,
                              hipStream_t stream) {
  const float* points = (const float*)d_in[0];
  LayerPtrs P;
  for (int i = 0; i < 8; ++i) {
    P.w[i] = (const float*)d_in[1 + 2 * i];
    P.b[i] = (const float*)d_in[2 + 2 * i];
  }
  const float* wsdf = (const float*)d_in[17];
  const float* bsdf = (const float*)d_in[18];
  f16x8* wf = (f16x8*)d_ws;   // needs 966656 B

  int N = in_sizes[0] / 3;    // 262144
  prep_weights<<<236, 256, 0, stream>>>(P, wf);
  mlp_fused<<<N / PTS, 256, 0, stream>>>(points, P, wf, wsdf, bsdf, (float*)d_out);
}

// Round 11
// 312.361 us; speedup vs baseline: 1.0452x; 1.0452x over previous
//
#include <hip/hip_runtime.h>
#include <hip/hip_fp16.h>

typedef _Float16 f16x8 __attribute__((ext_vector_type(8)));
typedef _Float16 f16x4 __attribute__((ext_vector_type(4)));
typedef _Float16 f16x2 __attribute__((ext_vector_type(2)));
typedef float    f32x16 __attribute__((ext_vector_type(16)));
typedef float    f32x4 __attribute__((ext_vector_type(4)));

#define SH 264   // H row stride (fp16): 256+8
#define SE 56    // E row stride (fp16)
#define PTS 128  // points per block

struct LayerPtrs {
  const float* w[8];
  const float* b[8];
};

// Weight fragments in d_ws, A-operand layout for mfma_f32_32x32x16_f16:
//   m = mtile*32 + (lane&31), k = kc*16 + (lane>>5)*8 + j ; value = W[k][m]
// index = WOFF[l] + (kc*8 + mtile)*64 + lane, element j.
__global__ void prep_weights(LayerPtrs P, f16x8* __restrict__ wf) {
  int gid = blockIdx.x * 256 + threadIdx.x;
  if (gid >= 60416) return;
  const int OFF[9] = {0,1536,9728,17920,26112,35840,44032,52224,60416};
  int l = 0;
  while (gid >= OFF[l+1]) ++l;
  int f = gid - OFF[l];
  int lane = f & 63;
  int t = f >> 6;
  int mtile = t & 7;
  int kc = t >> 3;
  int col = mtile * 32 + (lane & 31);
  int kb  = (lane >> 5) * 8;
  const float* w = P.w[l];
  f16x8 v;
#pragma unroll
  for (int j = 0; j < 8; ++j) {
    float x = 0.f;
    if (l == 4) {
      if (kc < 3) {
        int k = kc * 16 + kb + j;
        if (k < 39) x = w[k * 256 + col];
      } else {
        int k = (kc - 3) * 16 + kb + j;
        x = w[(39 + k) * 256 + col];
      }
    } else if (l == 0) {
      int k = kc * 16 + kb + j;
      if (k < 39) x = w[k * 256 + col];
    } else {
      int k = kc * 16 + kb + j;
      x = w[k * 256 + col];
    }
    v[j] = (_Float16)x;
  }
  wf[gid] = v;
}

struct WPre { f16x8 a0, a1; };          // kc0 weight frags (2 m-tiles)
struct BPre { f32x4 v[8]; };            // bias quads: [mt*4+g]

__device__ __forceinline__ WPre wpre(const f16x8* __restrict__ wb) {
  WPre p; p.a0 = wb[0]; p.a1 = wb[64]; return p;
}

__device__ __forceinline__ BPre bias_pre(const float* __restrict__ bp, int h) {
  BPre r;
#pragma unroll
  for (int mt = 0; mt < 2; ++mt)
#pragma unroll
    for (int g = 0; g < 4; ++g)
      r.v[mt * 4 + g] = *(const f32x4*)&bp[mt * 32 + 8 * g + 4 * h];
  return r;
}

// Bias pre-loaded into the accumulator (C/D reg 4g+r holds hidden 8g+4h+r).
__device__ __forceinline__ void init_acc(f32x16 acc[2][4], const BPre& bp) {
#pragma unroll
  for (int mt = 0; mt < 2; ++mt)
#pragma unroll
    for (int g = 0; g < 4; ++g) {
      f32x4 bv = bp.v[mt * 4 + g];
#pragma unroll
      for (int nt = 0; nt < 4; ++nt)
#pragma unroll
        for (int r = 0; r < 4; ++r)
          acc[mt][nt][4 * g + r] = bv[r];
    }
}

// Wave = 64 hidden (2 m-tiles) x 128 points (4 n-tiles): 8 MFMA per kc.
// PRE: kc0's weight frags come pre-loaded (fetched before the last barrier).
template<int NKC, bool PRE>
__device__ __forceinline__ void mm(const f16x8* __restrict__ wb,
                                   const _Float16* __restrict__ b0,
                                   const _Float16* __restrict__ b1,
                                   const _Float16* __restrict__ b2,
                                   const _Float16* __restrict__ b3,
                                   f32x16 acc[2][4], WPre p) {
#pragma unroll
  for (int kc = 0; kc < NKC; ++kc) {
    f16x8 a0 = (PRE && kc == 0) ? p.a0 : wb[(kc * 8 + 0) * 64];
    f16x8 a1 = (PRE && kc == 0) ? p.a1 : wb[(kc * 8 + 1) * 64];
    f16x8 v0 = *(const f16x8*)(b0 + kc * 16);
    f16x8 v1 = *(const f16x8*)(b1 + kc * 16);
    f16x8 v2 = *(const f16x8*)(b2 + kc * 16);
    f16x8 v3 = *(const f16x8*)(b3 + kc * 16);
    acc[0][0] = __builtin_amdgcn_mfma_f32_32x32x16_f16(a0, v0, acc[0][0], 0, 0, 0);
    acc[0][1] = __builtin_amdgcn_mfma_f32_32x32x16_f16(a0, v1, acc[0][1], 0, 0, 0);
    acc[0][2] = __builtin_amdgcn_mfma_f32_32x32x16_f16(a0, v2, acc[0][2], 0, 0, 0);
    acc[0][3] = __builtin_amdgcn_mfma_f32_32x32x16_f16(a0, v3, acc[0][3], 0, 0, 0);
    acc[1][0] = __builtin_amdgcn_mfma_f32_32x32x16_f16(a1, v0, acc[1][0], 0, 0, 0);
    acc[1][1] = __builtin_amdgcn_mfma_f32_32x32x16_f16(a1, v1, acc[1][1], 0, 0, 0);
    acc[1][2] = __builtin_amdgcn_mfma_f32_32x32x16_f16(a1, v2, acc[1][2], 0, 0, 0);
    acc[1][3] = __builtin_amdgcn_mfma_f32_32x32x16_f16(a1, v3, acc[1][3], 0, 0, 0);
  }
}

// Epilogue: packed cvt then packed f16 relu (bias already in acc).
// relu(cvt_rtz(x)) == cvt_rtz(relu(x)) since cvt preserves sign.
__device__ __forceinline__ f16x4 relu_cvt4(float a0, float a1, float a2, float a3) {
  f16x2 lo = __builtin_bit_cast(f16x2, __builtin_amdgcn_cvt_pkrtz(a0, a1));
  f16x2 hi = __builtin_bit_cast(f16x2, __builtin_amdgcn_cvt_pkrtz(a2, a3));
  union { f16x4 v; f16x2 h[2]; } u;
  u.h[0] = lo; u.h[1] = hi;
  f16x4 z = {};
  return __builtin_elementwise_max(u.v, z);   // 2x v_pk_max_f16
}

// C/D 32x32: col(point) = lane&31, row(hidden) = (reg&3) + 8*(reg>>2) + 4*(lane>>5)
__device__ __forceinline__ void store_act(f32x16 acc[2][4], int wg,
                                          int lane, _Float16* __restrict__ H) {
  int p0 = lane & 31, h = lane >> 5;
#pragma unroll
  for (int mt = 0; mt < 2; ++mt) {
    int hb = wg * 64 + mt * 32 + 4 * h;
#pragma unroll
    for (int g = 0; g < 4; ++g) {
#pragma unroll
      for (int nt = 0; nt < 4; ++nt) {
        f16x4 o = relu_cvt4(acc[mt][nt][4 * g + 0], acc[mt][nt][4 * g + 1],
                            acc[mt][nt][4 * g + 2], acc[mt][nt][4 * g + 3]);
        *(f16x4*)&H[(nt * 32 + p0) * SH + hb + 8 * g] = o;
      }
    }
  }
}

__global__ __launch_bounds__(256, 2)
void mlp_fused(const float* __restrict__ points,
               LayerPtrs P,
               const f16x8* __restrict__ wf,
               const float* __restrict__ wsdf,
               const float* __restrict__ bsdf,
               float* __restrict__ out) {
  __shared__ __align__(16) _Float16 H[PTS * SH];   // 67584 B
  __shared__ __align__(16) _Float16 E[PTS * SE];   // 14336 B -> 81920 total, 2 blocks/CU
  const int tid = threadIdx.x;
  const int blk = blockIdx.x;

  const int lane = tid & 63;
  const int wg   = tid >> 6;          // wave -> hidden slice [64*wg, 64*wg+64)
  const int p0   = lane & 31;
  const int h    = lane >> 5;

  const f16x8* wb = wf + (wg * 2) * 64 + lane;   // + WOFF[l] + (kc*8+mt)*64
  const int WOFF[8] = {0,1536,9728,17920,26112,35840,44032,52224};

  // Prefetch L0 weights + bias before the (long) embedding VALU phase.
  WPre wp = wpre(wb + WOFF[0]);
  BPre bp = bias_pre(P.b[0] + wg * 64, h);

  // ---- embedding into E: cols 0..38 = [sin(18)|cos(18)|xyz], 39..55 zero ----
  if (tid < PTS) {
    int p = blk * PTS + tid;
    float xyz[3] = {points[p * 3 + 0], points[p * 3 + 1], points[p * 3 + 2]};
    _Float16* row = &E[tid * SE];
#pragma unroll
    for (int c = 0; c < 3; ++c) {
      float fr = 1.f;
#pragma unroll
      for (int k = 0; k < 6; ++k) {
        float e = xyz[c] * fr;
        row[c * 6 + k]      = (_Float16)sinf(e);
        row[18 + c * 6 + k] = (_Float16)cosf(e);
        fr *= 2.f;
      }
      row[36 + c] = (_Float16)xyz[c];
    }
#pragma unroll
    for (int c = 39; c < SE; ++c) row[c] = (_Float16)0.f;
  }
  __syncthreads();

  const _Float16* e0 = &E[p0 * SE + h * 8];
  const _Float16* e1 = &E[(32 + p0) * SE + h * 8];
  const _Float16* e2 = &E[(64 + p0) * SE + h * 8];
  const _Float16* e3 = &E[(96 + p0) * SE + h * 8];
  const _Float16* h0 = &H[p0 * SH + h * 8];
  const _Float16* h1 = &H[(32 + p0) * SH + h * 8];
  const _Float16* h2 = &H[(64 + p0) * SH + h * 8];
  const _Float16* h3 = &H[(96 + p0) * SH + h * 8];

  f32x16 acc[2][4];

  // L0: read E, write H (disjoint -> no barrier between mm and store)
  init_acc(acc, bp);
  mm<3, true>(wb + WOFF[0], e0, e1, e2, e3, acc, wp);
  bp = bias_pre(P.b[1] + wg * 64, h);     // next-layer bias, pre-barrier
  wp = wpre(wb + WOFF[1]);                // next-layer kc0 weights
  store_act(acc, wg, lane, H);
  __syncthreads();

  // L1..L3: in-place H
#pragma unroll
  for (int l = 1; l < 4; ++l) {
    init_acc(acc, bp);
    mm<16, true>(wb + WOFF[l], h0, h1, h2, h3, acc, wp);
    bp = bias_pre(P.b[l + 1] + wg * 64, h);
    wp = wpre(wb + WOFF[l + 1]);
    __syncthreads();
    store_act(acc, wg, lane, H);
    __syncthreads();
  }

  // L4: concat input = E (3 kc, prefetched) + H (16 kc)
  init_acc(acc, bp);
  mm<3, true>(wb + WOFF[4], e0, e1, e2, e3, acc, wp);
  mm<16, false>(wb + WOFF[4] + 3 * 512, h0, h1, h2, h3, acc, wp);
  bp = bias_pre(P.b[5] + wg * 64, h);
  wp = wpre(wb + WOFF[5]);
  __syncthreads();
  store_act(acc, wg, lane, H);
  __syncthreads();

  // L5..L7
#pragma unroll
  for (int l = 5; l < 8; ++l) {
    init_acc(acc, bp);
    mm<16, true>(wb + WOFF[l], h0, h1, h2, h3, acc, wp);
    bp = bias_pre(P.b[l < 7 ? l + 1 : 7] + wg * 64, h);   // l=7: harmless refetch
    wp = wpre(wb + WOFF[l < 7 ? l + 1 : 7]);
    __syncthreads();
    store_act(acc, wg, lane, H);
    __syncthreads();
  }

  // ---- SDF head: 2 threads per point (PTS=128, 256 threads) ----
  {
    const int p = tid >> 1, part = tid & 1;
    float a = 0.f;
    const _Float16* xr = &H[p * SH + part * 128];
#pragma unroll
    for (int j = 0; j < 16; ++j) {
      f16x8 hh = *(const f16x8*)&xr[j * 8];
      f32x4 wa = *(const f32x4*)&wsdf[part * 128 + j * 8];
      f32x4 wc = *(const f32x4*)&wsdf[part * 128 + j * 8 + 4];
      a += (float)hh[0] * wa[0] + (float)hh[1] * wa[1]
         + (float)hh[2] * wa[2] + (float)hh[3] * wa[3]
         + (float)hh[4] * wc[0] + (float)hh[5] * wc[1]
         + (float)hh[6] * wc[2] + (float)hh[7] * wc[3];
    }
    a += __shfl_down(a, 1);
    if (part == 0) out[blk * PTS + p] = a + bsdf[0];
  }
}

extern "C" void kernel_launch(void* const* d_in, const int* in_sizes, int n_in,
                              void* d_out, int out_size, void* d_ws, size_t ws_size,
                              hipStream_t stream) {
  const float* points = (const float*)d_in[0];
  LayerPtrs P;
  for (int i = 0; i < 8; ++i) {
    P.w[i] = (const float*)d_in[1 + 2 * i];
    P.b[i] = (const float*)d_in[2 + 2 * i];
  }
  const float* wsdf = (const float*)d_in[17];
  const float* bsdf = (const float*)d_in[18];
  f16x8* wf = (f16x8*)d_ws;   // needs 966656 B

  int N = in_sizes[0] / 3;    // 262144
  prep_weights<<<236, 256, 0, stream>>>(P, wf);
  mlp_fused<<<N / PTS, 256, 0, stream>>>(points, P, wf, wsdf, bsdf, (float*)d_out);
}